// Round 4
// baseline (28248.660 us; speedup 1.0000x reference)
//
#include <hip/hip_runtime.h>
#include <math.h>

#define VOCAB 8000
#define EMB   512
#define HID   1024
#define SEQ_L 1024
#define G3    (3*HID)
#define NROLE 64          // recurrence roles (64 x 16 h-elements)
#define NWG_L 512         // launched WGs: 2/CU x 256 CUs; exactly 64 land per XCD
#define POISON 0xAAAAAAAAu
#define CLAIMTAG 0x5AB00000u

typedef float v2f __attribute__((ext_vector_type(2)));
typedef float v4f __attribute__((ext_vector_type(4)));

// 16B load bypassing L1+L2 (reads the Infinity Cache coherence point)
__device__ __forceinline__ v4f ic_load4(const float* p) {
  v4f r;
  asm volatile("global_load_dwordx4 %0, %1, off sc0 sc1\n\ts_waitcnt vmcnt(0)"
               : "=v"(r) : "v"(p) : "memory");
  return r;
}
// 16B load bypassing L1 only (hits the local XCD L2 — same-XCD coherence point)
__device__ __forceinline__ v4f l2_load4(const float* p) {
  v4f r;
  asm volatile("global_load_dwordx4 %0, %1, off sc0\n\ts_waitcnt vmcnt(0)"
               : "=v"(r) : "v"(p) : "memory");
  return r;
}
// store visible at local XCD L2 (write-through L1)
__device__ __forceinline__ void l2_storef(float* p, float v) {
  asm volatile("global_store_dword %0, %1, off sc0" :: "v"(p), "v"(v) : "memory");
}
__device__ __forceinline__ bool any_poison4(v4f v) {
  return __float_as_uint(v.x) == POISON || __float_as_uint(v.y) == POISON ||
         __float_as_uint(v.z) == POISON || __float_as_uint(v.w) == POISON;
}
// device-scope publish (executes at Infinity Cache) with anti-poison squash
__device__ __forceinline__ void publishf(float* p, float v) {
  if (__float_as_uint(v) == POISON) v = __uint_as_float(POISON ^ 1u);
  atomicExch(p, v);
}
// sum within each 16-lane row, VALU-only via DPP
__device__ __forceinline__ float row16_sum(float x) {
  int v = __float_as_int(x);
  x += __int_as_float(__builtin_amdgcn_update_dpp(0, v, 0xB1,  0xF, 0xF, false)); v = __float_as_int(x);
  x += __int_as_float(__builtin_amdgcn_update_dpp(0, v, 0x4E,  0xF, 0xF, false)); v = __float_as_int(x);
  x += __int_as_float(__builtin_amdgcn_update_dpp(0, v, 0x141, 0xF, 0xF, false)); v = __float_as_int(x);
  x += __int_as_float(__builtin_amdgcn_update_dpp(0, v, 0x140, 0xF, 0xF, false));
  return x;
}

// ---------------- prep: dec_in + valid mask ----------------
__global__ __launch_bounds__(1024) void prep_kernel(
    const int* __restrict__ target, const int* __restrict__ sos_p,
    const int* __restrict__ eos_p, int* __restrict__ dec_in,
    float* __restrict__ valid)
{
  int t = threadIdx.x;
  int eos = eos_p[0];
  dec_in[t] = (t == 0) ? sos_p[0] : target[t - 1];
  bool ne = (target[t] != eos);
  unsigned long long b = __ballot(ne);
  int lane = t & 63, w = t >> 6;
  __shared__ unsigned long long wb[16];
  if (lane == 0) wb[w] = b;
  __syncthreads();
  bool ok = (((~b) & ((1ull << lane) - 1ull)) == 0ull);
  for (int i = 0; i < 16; i++)
    if (i < w) ok = ok && (wb[i] == ~0ull);
  valid[t] = ok ? 1.0f : 0.0f;
}

// ---------------- fp32 NT GEMM: C[m][n] = dot(A[m][:K], B[n][:K]) + bias[n], x rowscale[m]
__global__ __launch_bounds__(256) void gemm_nt(
    const float* __restrict__ A, const int* __restrict__ idx,
    const float* __restrict__ B, const float* __restrict__ bias,
    const float* __restrict__ rowscale, float* __restrict__ C,
    int M, int N, int K)
{
  __shared__ __align__(16) float As[16][132];
  __shared__ __align__(16) float Bs[16][132];
  const int tid = threadIdx.x;
  const int bm = blockIdx.y * 128;
  const int bn = blockIdx.x * 128;
  const int tx = tid & 15, ty = tid >> 4;
  float acc[8][8];
#pragma unroll
  for (int i = 0; i < 8; i++)
#pragma unroll
    for (int jj = 0; jj < 8; jj++) acc[i][jj] = 0.f;

  for (int k0 = 0; k0 < K; k0 += 16) {
    __syncthreads();
#pragma unroll
    for (int r = 0; r < 2; r++) {
      int v = tid + 256 * r;
      int row = v >> 2;
      int kq = (v & 3) << 2;
      int m = bm + row;
      const float* abase = idx ? (A + (size_t)idx[m] * K) : (A + (size_t)m * K);
      float4 av = *(const float4*)(abase + k0 + kq);
      As[kq + 0][row] = av.x; As[kq + 1][row] = av.y;
      As[kq + 2][row] = av.z; As[kq + 3][row] = av.w;
      int n = bn + row;
      float4 bv = make_float4(0.f, 0.f, 0.f, 0.f);
      if (n < N) bv = *(const float4*)(B + (size_t)n * K + k0 + kq);
      Bs[kq + 0][row] = bv.x; Bs[kq + 1][row] = bv.y;
      Bs[kq + 2][row] = bv.z; Bs[kq + 3][row] = bv.w;
    }
    __syncthreads();
#pragma unroll
    for (int k = 0; k < 16; k++) {
      float am[8], bb[8];
      *(float4*)&am[0] = *(const float4*)&As[k][ty * 8];
      *(float4*)&am[4] = *(const float4*)&As[k][ty * 8 + 4];
      *(float4*)&bb[0] = *(const float4*)&Bs[k][tx * 8];
      *(float4*)&bb[4] = *(const float4*)&Bs[k][tx * 8 + 4];
#pragma unroll
      for (int i = 0; i < 8; i++)
#pragma unroll
        for (int jj = 0; jj < 8; jj++)
          acc[i][jj] += am[i] * bb[jj];
    }
  }
#pragma unroll
  for (int i = 0; i < 8; i++) {
    int m = bm + ty * 8 + i;
    float rs = rowscale ? rowscale[m] : 1.0f;
#pragma unroll
    for (int jj = 0; jj < 8; jj++) {
      int n = bn + tx * 8 + jj;
      if (n < N) C[(size_t)m * N + n] = (acc[i][jj] + bias[n]) * rs;
    }
  }
}

// ---------------- persistent GRU recurrence: XCD-local handoff ----------------
// Round-3 falsified poll-pipelining (same-line loads MSHR-merge); step time is
// fixed IC round-trips. This round: co-locate all 64 roles on ONE XCD and hand
// off through its L2 (~150-300cy RTT vs ~1000+ to IC).
//  * 512 WGs launched (2/CU fills the chip => exactly 64 per XCD). WGs read
//    HW_REG_XCC_ID; CAS-elected leader XCD's WGs claim 64 role slots
//    (poison-CAS). Others wait as backfill insurance, then exit.
//  * publish: global_store sc0 (write-through to local L2). poll: dwordx4 sc0
//    (L1-bypass, L2-hit). Kernel-end L2 writeback makes results visible to the
//    later gemm dispatches on any XCD.
//  * hang-proofing: (1) bounded pre-flight self-test of the L2 handshake;
//    failure => dual-publish (sc0 store + device atomicExch belt) + IC-
//    alternating polls. (2) roles claimed cross-XCD (backfill) are known at
//    claim time: their chunks pre-set to alternating polls, all publishers go
//    dual. (3) in-loop watchdog: 4096 spins => alternate L2+IC reads (L2 is
//    never abandoned, so a slow-but-local owner cannot deadlock a poller).
//    Every degraded path ~= the round-0 IC design; never a hang.
//  * waves 0-3 (pollers) issue no pre-poll VMEM: their gi operands are proxy-
//    loaded by waves 8-11 into parity-double-buffered LDS, so the poll vmcnt
//    drain covers poll loads only.
__global__ __launch_bounds__(1024, 8) void recur_kernel(
    const float* __restrict__ enc_whh, const float* __restrict__ enc_bhh,
    const float* __restrict__ dec_whh, const float* __restrict__ dec_bhh,
    const float* __restrict__ enc_state, const int* __restrict__ char_seq,
    const float* __restrict__ gi_enc, const float* __restrict__ gi_dec,
    float* hbuf, unsigned* ctrl, float* testrow)
{
  const int tid  = threadIdx.x;
  const int lane = tid & 63;
  const int w    = tid >> 6;           // wave id = owned element within slice

  __shared__ __align__(16) float hLDS[HID];
  __shared__ float giLDS[2][4][3];     // parity-buffered proxy gi for waves 0-3
  __shared__ int   csLDS[2];
  __shared__ int   roleLDS;
  __shared__ unsigned m0LDS, m1LDS;    // remote-role mask (vs my XCD)
  __shared__ int   dualLDS;            // publishers: also belt to IC
  __shared__ int   tfailLDS;           // L2 self-test failure

  // ---- claim a role (tid 0 only; others wait at the barrier) ----
  if (tid == 0) {
    tfailLDS = 0;
    unsigned xcc = ((unsigned)__builtin_amdgcn_s_getreg(63508)) & 0xFu; // HW_REG_XCC_ID
    unsigned old = atomicCAS(&ctrl[0], POISON, CLAIMTAG | xcc);
    unsigned lead = (old == POISON) ? xcc : (old & 0xFu);
    int role = -1;
    if (xcc == lead) {
      int r0 = ((int)blockIdx.x * 7) & 63;
      for (int i = 0; i < NROLE && role < 0; i++) {
        int r = (r0 + i) & 63;
        if (atomicCAS(&ctrl[1 + r], POISON, CLAIMTAG | xcc) == POISON) role = r;
      }
    }
    // wait for the full table; non-members backfill leftover roles if the
    // leader XCD came up short (insurance; never fires with uniform dispatch)
    int pass = 0;
    for (;;) {
      int unclaimed = 0;
      for (int r = 0; r < NROLE; r++) {
        unsigned v = __hip_atomic_load(&ctrl[1 + r], __ATOMIC_RELAXED,
                                       __HIP_MEMORY_SCOPE_AGENT);
        if (v == POISON) unclaimed++;
      }
      if (!unclaimed) break;
      if (role < 0 && ++pass > 8) {
        for (int r = 0; r < NROLE && role < 0; r++)
          if (atomicCAS(&ctrl[1 + r], POISON, CLAIMTAG | xcc) == POISON) role = r;
      } else {
        __builtin_amdgcn_s_sleep(64);
      }
    }
    unsigned m0 = 0, m1 = 0;
    for (int r = 0; r < NROLE; r++) {
      unsigned v = __hip_atomic_load(&ctrl[1 + r], __ATOMIC_RELAXED,
                                     __HIP_MEMORY_SCOPE_AGENT);
      if ((v & 0xFu) != xcc) { if (r < 32) m0 |= 1u << r; else m1 |= 1u << (r - 32); }
    }
    roleLDS = role; m0LDS = m0; m1LDS = m1;
    dualLDS = (m0 | m1) ? 1 : 0;
  }
  __syncthreads();
  const int role = roleLDS;
  if (role < 0) return;                 // non-member: exit (CU freed)
  const int j = role * 16 + w;          // owned global h index (per wave)

  const bool isPoller = (tid < 256);
  bool alt = false;                     // poll mode: false=L2-only, true=L2+IC
  if (isPoller) {
    int owner = tid >> 2;               // role owning my 16B chunk
    unsigned mm = (owner < 32) ? m0LDS : m1LDS;
    alt = ((mm >> (owner & 31)) & 1u) != 0;
  }

  // ---- bounded pre-flight self-test of the L2 handshake ----
  if (lane == 0) l2_storef(&testrow[j], 3.0f);
  if (isPoller && !alt) {
    const float* tp = testrow + 4 * tid;
    int spins = 0;
    for (;;) {
      v4f t = l2_load4(tp);
      if (!any_poison4(t)) break;
      if (++spins == 4096) { atomicOr(&tfailLDS, 1); break; }
    }
  }
  __syncthreads();
  int dual = dualLDS | tfailLDS;
  if (tfailLDS && isPoller) alt = true;

  // ---- publish h0 (always dual: one-time, costless) ----
  if (lane == 0) {
    float v0 = enc_state[j];
    if (__float_as_uint(v0) == POISON) v0 = __uint_as_float(POISON ^ 1u);
    l2_storef(&hbuf[j], v0);
    publishf(&hbuf[j], v0);
  }

  // ---- weights -> 48 VGPRs (24 v2f) per thread ----
  v2f wv[3][8];
#pragma unroll
  for (int g = 0; g < 3; g++) {
    const float* wrow = enc_whh + (size_t)(g * HID + j) * HID + lane * 16;
#pragma unroll
    for (int u = 0; u < 4; u++) {
      v4f t4 = *(const v4f*)(wrow + u * 4);
      wv[g][2 * u]     = (v2f){t4.x, t4.y};
      wv[g][2 * u + 1] = (v2f){t4.z, t4.w};
    }
  }
  float bhr = enc_bhh[j], bhz = enc_bhh[HID + j], bhn = enc_bhh[2 * HID + j];

  for (int s = 1; s <= 2 * SEQ_L; s++) {
    if (s == SEQ_L + 1) {              // switch to decoder weights
#pragma unroll
      for (int g = 0; g < 3; g++) {
        const float* wrow = dec_whh + (size_t)(g * HID + j) * HID + lane * 16;
#pragma unroll
        for (int u = 0; u < 4; u++) {
          v4f t4 = *(const v4f*)(wrow + u * 4);
          wv[g][2 * u]     = (v2f){t4.x, t4.y};
          wv[g][2 * u + 1] = (v2f){t4.z, t4.w};
        }
      }
      bhr = dec_bhh[j]; bhz = dec_bhh[HID + j]; bhn = dec_bhh[2 * HID + j];
    }

    const float* gi = (s <= SEQ_L) ? (gi_enc + (size_t)(s - 1) * G3)
                                   : (gi_dec + (size_t)(s - SEQ_L - 1) * G3);
    const int par = s & 1;
    float gir = 0.f, giz = 0.f, gin = 0.f;
    int cs = 1;
    if (lane == 0 && w >= 4) {         // non-poller waves: self-load gi
      gir = gi[j]; giz = gi[HID + j]; gin = gi[2 * HID + j];
      if (s <= SEQ_L) cs = char_seq[s - 1];
    }
    if (lane == 0 && w >= 8 && w < 12) {  // proxy gi for poller waves 0-3
      int pj = role * 16 + (w - 8);
      float a = gi[pj], b = gi[HID + pj], c = gi[2 * HID + pj];
      giLDS[par][w - 8][0] = a; giLDS[par][w - 8][1] = b; giLDS[par][w - 8][2] = c;
      if (w == 8) csLDS[par] = (s <= SEQ_L) ? char_seq[s - 1] : 1;
    }

    // ---- poll h_{s-1}: 256 threads x 16B at the local L2 ----
    if (isPoller) {
      const float* hp = hbuf + (size_t)(s - 1) * HID + 4 * tid;
      v4f hv;
      int spins = 0;
      for (;;) {
        hv = l2_load4(hp);
        if (!any_poison4(hv)) break;
        if (alt) {
          hv = ic_load4(hp);
          if (!any_poison4(hv)) break;
        } else if (++spins == 4096) {
          alt = true;                  // sticky: keep L2 reads, add IC reads
        }
      }
      int us = tid ^ ((tid >> 3) & 7);
      *(v4f*)&hLDS[us * 4] = hv;
    }
    __syncthreads();                    // the ONLY barrier per step
    if (lane == 0 && w < 4) {           // poller waves: gi from proxy LDS
      gir = giLDS[par][w][0]; giz = giLDS[par][w][1]; gin = giLDS[par][w][2];
      cs = csLDS[par];
    }
    int uj = j >> 2, usj = uj ^ ((uj >> 3) & 7);
    float hold = hLDS[usj * 4 + (j & 3)];
    // 48 MACs/thread on b128 LDS fragments (2-way bank aliasing = free)
    v2f acc2[3] = {(v2f){0.f, 0.f}, (v2f){0.f, 0.f}, (v2f){0.f, 0.f}};
#pragma unroll
    for (int u = 0; u < 4; u++) {
      int uu = lane * 4 + u, s2 = uu ^ ((uu >> 3) & 7);
      v4f hv = *(const v4f*)&hLDS[s2 * 4];
      v2f h0 = (v2f){hv.x, hv.y}, h1 = (v2f){hv.z, hv.w};
#pragma unroll
      for (int g = 0; g < 3; g++) {
        acc2[g] = __builtin_elementwise_fma(wv[g][2 * u], h0, acc2[g]);
        acc2[g] = __builtin_elementwise_fma(wv[g][2 * u + 1], h1, acc2[g]);
      }
    }
    // 64-lane reduce: DPP within 16 lanes, 2 shfl_xor across groups
    float gh[3];
#pragma unroll
    for (int g = 0; g < 3; g++) {
      float t = row16_sum(acc2[g].x + acc2[g].y);
      t += __shfl_xor(t, 16, 64);
      t += __shfl_xor(t, 32, 64);
      gh[g] = t;
    }
    if (lane == 0) {
      float ghr = gh[0] + bhr, ghz = gh[1] + bhz, ghn = gh[2] + bhn;
      float r = __builtin_amdgcn_rcpf(1.f + __expf(-(gir + ghr)));
      float z = __builtin_amdgcn_rcpf(1.f + __expf(-(giz + ghz)));
      float x = gin + r * ghn;
      float e = __expf(2.f * x);
      float n = 1.f - 2.f * __builtin_amdgcn_rcpf(e + 1.f);   // fast tanh
      float hnew = (1.f - z) * n + z * hold;
      if (s <= SEQ_L && cs == 0) hnew = hold;                 // encoder mask
      if (__float_as_uint(hnew) == POISON) hnew = __uint_as_float(POISON ^ 1u);
      l2_storef(&hbuf[(size_t)s * HID + j], hnew);            // fast local path
      if (dual) publishf(&hbuf[(size_t)s * HID + j], hnew);   // IC belt
    }
    // no second barrier: pollers can only overwrite hLDS after detecting all
    // of row s, which requires every local wave's publish, which follows that
    // wave's hLDS reads.
  }
}

// ---------------- states output: hdec * valid ----------------
__global__ __launch_bounds__(256) void states_kernel(
    const float* __restrict__ hdec, const float* __restrict__ valid,
    float* __restrict__ out2)
{
  int i = blockIdx.x * 256 + threadIdx.x;
  out2[i] = hdec[i] * valid[i >> 10];
}

extern "C" void kernel_launch(void* const* d_in, const int* in_sizes, int n_in,
                              void* d_out, int out_size, void* d_ws, size_t ws_size,
                              hipStream_t stream)
{
  const int*   char_seq  = (const int*)  d_in[0];
  const int*   target    = (const int*)  d_in[1];
  const float* enc_state = (const float*)d_in[2];
  const float* emb       = (const float*)d_in[3];
  const float* enc_wih   = (const float*)d_in[4];
  const float* enc_whh   = (const float*)d_in[5];
  const float* enc_bih   = (const float*)d_in[6];
  const float* enc_bhh   = (const float*)d_in[7];
  const float* dec_wih   = (const float*)d_in[8];
  const float* dec_whh   = (const float*)d_in[9];
  const float* dec_bih   = (const float*)d_in[10];
  const float* dec_bhh   = (const float*)d_in[11];
  const float* out_w     = (const float*)d_in[12];
  const float* out_b     = (const float*)d_in[13];
  const int*   sos_p     = (const int*)  d_in[14];
  const int*   eos_p     = (const int*)  d_in[15];

  char* ws = (char*)d_ws;
  float* gi_enc  = (float*)ws;  ws += (size_t)SEQ_L * G3 * sizeof(float);
  float* gi_dec  = (float*)ws;  ws += (size_t)SEQ_L * G3 * sizeof(float);
  float* hbuf    = (float*)ws;  ws += (size_t)(2 * SEQ_L + 1) * HID * sizeof(float);
  float* valid   = (float*)ws;  ws += SEQ_L * sizeof(float);
  int*   dec_in  = (int*)ws;    ws += SEQ_L * sizeof(int);
  unsigned* ctrl = (unsigned*)ws; ws += 128 * sizeof(unsigned);  // [0]=leader, [1..64]=slots
  float* testrow = (float*)ws;  ws += HID * sizeof(float);

  // decode step d (1..SEQ_L) writes hbuf row SEQ_L+d  ->  hdec = hbuf[SEQ_L+1]
  float* hdec = hbuf + (size_t)(SEQ_L + 1) * HID;

  float* out_scores = (float*)d_out;
  float* out_states = out_scores + (size_t)SEQ_L * VOCAB;

  prep_kernel<<<1, 1024, 0, stream>>>(target, sos_p, eos_p, dec_in, valid);
  gemm_nt<<<dim3(G3 / 128, SEQ_L / 128), 256, 0, stream>>>(
      emb, char_seq, enc_wih, enc_bih, nullptr, gi_enc, SEQ_L, G3, EMB);
  gemm_nt<<<dim3(G3 / 128, SEQ_L / 128), 256, 0, stream>>>(
      emb, dec_in, dec_wih, dec_bih, nullptr, gi_dec, SEQ_L, G3, EMB);
  recur_kernel<<<NWG_L, 1024, 0, stream>>>(
      enc_whh, enc_bhh, dec_whh, dec_bhh, enc_state, char_seq,
      gi_enc, gi_dec, hbuf, ctrl, testrow);
  gemm_nt<<<dim3((VOCAB + 127) / 128, SEQ_L / 128), 256, 0, stream>>>(
      hdec, nullptr, out_w, out_b, valid, out_scores, SEQ_L, VOCAB, HID);
  states_kernel<<<(SEQ_L * HID) / 256, 256, 0, stream>>>(hdec, valid, out_states);
}

// Round 5
// 4237.183 us; speedup vs baseline: 6.6668x; 6.6668x over previous
//
#include <hip/hip_runtime.h>
#include <math.h>

#define VOCAB 8000
#define EMB   512
#define HID   1024
#define SEQ_L 1024
#define G3    (3*HID)
#define NWG   64          // recurrence workgroups (co-resident: 64 <= 256 CUs)
#define POISON 0xAAAAAAAAu

typedef float v2f __attribute__((ext_vector_type(2)));
typedef float v4f __attribute__((ext_vector_type(4)));

// 16B load that bypasses L1+L2 (reads the Infinity Cache coherence point)
__device__ __forceinline__ v4f ic_load4(const float* p) {
  v4f r;
  asm volatile("global_load_dwordx4 %0, %1, off sc0 sc1\n\ts_waitcnt vmcnt(0)"
               : "=v"(r) : "v"(p) : "memory");
  return r;
}
__device__ __forceinline__ bool any_poison4(v4f v) {
  return __float_as_uint(v.x) == POISON || __float_as_uint(v.y) == POISON ||
         __float_as_uint(v.z) == POISON || __float_as_uint(v.w) == POISON;
}
// sum within each 16-lane row, VALU-only via DPP
__device__ __forceinline__ float row16_sum(float x) {
  int v = __float_as_int(x);
  x += __int_as_float(__builtin_amdgcn_update_dpp(0, v, 0xB1,  0xF, 0xF, false)); v = __float_as_int(x);
  x += __int_as_float(__builtin_amdgcn_update_dpp(0, v, 0x4E,  0xF, 0xF, false)); v = __float_as_int(x);
  x += __int_as_float(__builtin_amdgcn_update_dpp(0, v, 0x141, 0xF, 0xF, false)); v = __float_as_int(x);
  x += __int_as_float(__builtin_amdgcn_update_dpp(0, v, 0x140, 0xF, 0xF, false));
  return x;
}

// ---------------- prep: dec_in + valid mask ----------------
__global__ __launch_bounds__(1024) void prep_kernel(
    const int* __restrict__ target, const int* __restrict__ sos_p,
    const int* __restrict__ eos_p, int* __restrict__ dec_in,
    float* __restrict__ valid)
{
  int t = threadIdx.x;
  int eos = eos_p[0];
  dec_in[t] = (t == 0) ? sos_p[0] : target[t - 1];
  bool ne = (target[t] != eos);
  unsigned long long b = __ballot(ne);
  int lane = t & 63, w = t >> 6;
  __shared__ unsigned long long wb[16];
  if (lane == 0) wb[w] = b;
  __syncthreads();
  bool ok = (((~b) & ((1ull << lane) - 1ull)) == 0ull);
  for (int i = 0; i < 16; i++)
    if (i < w) ok = ok && (wb[i] == ~0ull);
  valid[t] = ok ? 1.0f : 0.0f;
}

// ---------------- fp32 NT GEMM: C[m][n] = dot(A[m][:K], B[n][:K]) + bias[n], x rowscale[m]
__global__ __launch_bounds__(256) void gemm_nt(
    const float* __restrict__ A, const int* __restrict__ idx,
    const float* __restrict__ B, const float* __restrict__ bias,
    const float* __restrict__ rowscale, float* __restrict__ C,
    int M, int N, int K)
{
  __shared__ __align__(16) float As[16][132];
  __shared__ __align__(16) float Bs[16][132];
  const int tid = threadIdx.x;
  const int bm = blockIdx.y * 128;
  const int bn = blockIdx.x * 128;
  const int tx = tid & 15, ty = tid >> 4;
  float acc[8][8];
#pragma unroll
  for (int i = 0; i < 8; i++)
#pragma unroll
    for (int jj = 0; jj < 8; jj++) acc[i][jj] = 0.f;

  for (int k0 = 0; k0 < K; k0 += 16) {
    __syncthreads();
#pragma unroll
    for (int r = 0; r < 2; r++) {
      int v = tid + 256 * r;
      int row = v >> 2;
      int kq = (v & 3) << 2;
      int m = bm + row;
      const float* abase = idx ? (A + (size_t)idx[m] * K) : (A + (size_t)m * K);
      float4 av = *(const float4*)(abase + k0 + kq);
      As[kq + 0][row] = av.x; As[kq + 1][row] = av.y;
      As[kq + 2][row] = av.z; As[kq + 3][row] = av.w;
      int n = bn + row;
      float4 bv = make_float4(0.f, 0.f, 0.f, 0.f);
      if (n < N) bv = *(const float4*)(B + (size_t)n * K + k0 + kq);
      Bs[kq + 0][row] = bv.x; Bs[kq + 1][row] = bv.y;
      Bs[kq + 2][row] = bv.z; Bs[kq + 3][row] = bv.w;
    }
    __syncthreads();
#pragma unroll
    for (int k = 0; k < 16; k++) {
      float am[8], bb[8];
      *(float4*)&am[0] = *(const float4*)&As[k][ty * 8];
      *(float4*)&am[4] = *(const float4*)&As[k][ty * 8 + 4];
      *(float4*)&bb[0] = *(const float4*)&Bs[k][tx * 8];
      *(float4*)&bb[4] = *(const float4*)&Bs[k][tx * 8 + 4];
#pragma unroll
      for (int i = 0; i < 8; i++)
#pragma unroll
        for (int jj = 0; jj < 8; jj++)
          acc[i][jj] += am[i] * bb[jj];
    }
  }
#pragma unroll
  for (int i = 0; i < 8; i++) {
    int m = bm + ty * 8 + i;
    float rs = rowscale ? rowscale[m] : 1.0f;
#pragma unroll
    for (int jj = 0; jj < 8; jj++) {
      int n = bn + tx * 8 + jj;
      if (n < N) C[(size_t)m * N + n] = (acc[i][jj] + bias[n]) * rs;
    }
  }
}

// ---------------- persistent GRU recurrence (runs ALONE on the GPU) ---------
// 64 WGs x 1024 threads. Wave w owns h element j = wg*16+w and whh rows
// {j, HID+j, 2*HID+j}; lane covers k in [lane*16, lane*16+16).
// Handoff: hbuf row s = h after s steps; consume = 256 threads x 16B sc0/sc1
// polls against the 0xAA poison the harness writes into d_ws.
// THIS ROUND: batched publish. Round-0/3 published via 16 atomicExch (one per
// wave) to the SAME 64B line -- same-line atomic RMWs serialize at the TCC
// (~1500cy/step, the largest unexplained step-time term). Now: lane0 of each
// wave drops hnew into pubLDS[w]; barrier; wave 0 lanes 0-15 issue ONE
// wave-coalesced agent-scope store (16 contiguous dwords = one 64B IC
// transaction). Poll side unchanged (round-3 proved same-line poll pipelining
// is MSHR-merged; round-4 proved XCD-local L2 handoff is placement-unsafe).
__global__ __launch_bounds__(1024, 1) void recur_kernel(
    const float* __restrict__ enc_whh, const float* __restrict__ enc_bhh,
    const float* __restrict__ dec_whh, const float* __restrict__ dec_bhh,
    const float* __restrict__ enc_state, const int* __restrict__ char_seq,
    const float* __restrict__ gi_enc, const float* __restrict__ gi_dec,
    float* hbuf)
{
  const int wg   = blockIdx.x;
  const int tid  = threadIdx.x;
  const int lane = tid & 63;
  const int w    = tid >> 6;           // wave id = owned element within slice
  const int j    = wg * 16 + w;        // owned global h index (per wave)

  __shared__ __align__(16) float hLDS[HID];
  __shared__ float pubLDS[16];

  // publish h0 slice (one coalesced agent store from wave 0, lanes 0-15);
  // warm rows 1..16 into IC (no-op RMW allocates the line)
  if (tid < 16) {
    float v0 = enc_state[wg * 16 + tid];
    if (__float_as_uint(v0) == POISON) v0 = __uint_as_float(POISON ^ 1u);
    __hip_atomic_store(&hbuf[wg * 16 + tid], v0,
                       __ATOMIC_RELAXED, __HIP_MEMORY_SCOPE_AGENT);
  }
  if (tid >= 960 && tid < 976)
    atomicOr((unsigned int*)&hbuf[(size_t)(tid - 959) * HID + wg * 16], 0u);

  // weights -> 48 VGPRs (24 v2f) per thread
  v2f wv[3][8];
#pragma unroll
  for (int g = 0; g < 3; g++) {
    const float* wrow = enc_whh + (size_t)(g * HID + j) * HID + lane * 16;
#pragma unroll
    for (int u = 0; u < 4; u++) {
      v4f t4 = *(const v4f*)(wrow + u * 4);
      wv[g][2 * u]     = (v2f){t4.x, t4.y};
      wv[g][2 * u + 1] = (v2f){t4.z, t4.w};
    }
  }
  float bhr = enc_bhh[j], bhz = enc_bhh[HID + j], bhn = enc_bhh[2 * HID + j];

  for (int s = 1; s <= 2 * SEQ_L; s++) {
    if (s == SEQ_L + 1) {              // switch to decoder weights
#pragma unroll
      for (int g = 0; g < 3; g++) {
        const float* wrow = dec_whh + (size_t)(g * HID + j) * HID + lane * 16;
#pragma unroll
        for (int u = 0; u < 4; u++) {
          v4f t4 = *(const v4f*)(wrow + u * 4);
          wv[g][2 * u]     = (v2f){t4.x, t4.y};
          wv[g][2 * u + 1] = (v2f){t4.z, t4.w};
        }
      }
      bhr = dec_bhh[j]; bhz = dec_bhh[HID + j]; bhn = dec_bhh[2 * HID + j];
    }
    if (tid == 976 && s + 16 <= 2 * SEQ_L)
      atomicOr((unsigned int*)&hbuf[(size_t)(s + 16) * HID + wg * 16], 0u);

    // gi prefetch (plain loads; gi fully materialized by earlier dispatches)
    float gir = 0.f, giz = 0.f, gin = 0.f;
    int cs = 1;
    if (lane == 0) {
      const float* gi = (s <= SEQ_L) ? (gi_enc + (size_t)(s - 1) * G3)
                                     : (gi_dec + (size_t)(s - SEQ_L - 1) * G3);
      gir = gi[j]; giz = gi[HID + j]; gin = gi[2 * HID + j];
      if (s <= SEQ_L) cs = char_seq[s - 1];
    }

    // poll h_{s-1}: 256 threads x 16B, tight loop, XOR-swizzled LDS store
    if (tid < 256) {
      const float* hp = hbuf + (size_t)(s - 1) * HID + 4 * tid;
      v4f hv = ic_load4(hp);
      while (any_poison4(hv)) hv = ic_load4(hp);
      int us = tid ^ ((tid >> 3) & 7);
      *(v4f*)&hLDS[us * 4] = hv;
    }
    __syncthreads();                    // barrier A: hLDS ready
    int uj = j >> 2, usj = uj ^ ((uj >> 3) & 7);
    float hold = hLDS[usj * 4 + (j & 3)];
    // 48 MACs/thread on b128 LDS fragments (2-way bank aliasing = free)
    v2f acc2[3] = {(v2f){0.f, 0.f}, (v2f){0.f, 0.f}, (v2f){0.f, 0.f}};
#pragma unroll
    for (int u = 0; u < 4; u++) {
      int uu = lane * 4 + u, s2 = uu ^ ((uu >> 3) & 7);
      v4f hv = *(const v4f*)&hLDS[s2 * 4];
      v2f h0 = (v2f){hv.x, hv.y}, h1 = (v2f){hv.z, hv.w};
#pragma unroll
      for (int g = 0; g < 3; g++) {
        acc2[g] = __builtin_elementwise_fma(wv[g][2 * u], h0, acc2[g]);
        acc2[g] = __builtin_elementwise_fma(wv[g][2 * u + 1], h1, acc2[g]);
      }
    }
    // 64-lane reduce: DPP within 16 lanes, 2 shfl_xor across groups
    float gh[3];
#pragma unroll
    for (int g = 0; g < 3; g++) {
      float t = row16_sum(acc2[g].x + acc2[g].y);
      t += __shfl_xor(t, 16, 64);
      t += __shfl_xor(t, 32, 64);
      gh[g] = t;
    }
    if (lane == 0) {
      float ghr = gh[0] + bhr, ghz = gh[1] + bhz, ghn = gh[2] + bhn;
      float r = __builtin_amdgcn_rcpf(1.f + __expf(-(gir + ghr)));
      float z = __builtin_amdgcn_rcpf(1.f + __expf(-(giz + ghz)));
      float x = gin + r * ghn;
      float e = __expf(2.f * x);
      float n = 1.f - 2.f * __builtin_amdgcn_rcpf(e + 1.f);   // fast tanh
      float hnew = (1.f - z) * n + z * hold;
      if (s <= SEQ_L && cs == 0) hnew = hold;                 // encoder mask
      pubLDS[w] = hnew;                 // gather for the coalesced publish
    }
    __syncthreads();                    // barrier B: pubLDS complete
    if (tid < 16) {
      float v = pubLDS[tid];
      if (__float_as_uint(v) == POISON) v = __uint_as_float(POISON ^ 1u);
      // ONE 64B wave-coalesced agent-scope store (commits at the IC); the
      // next poll's internal vmcnt(0) guarantees it is issued before spinning.
      __hip_atomic_store(&hbuf[(size_t)s * HID + wg * 16 + tid], v,
                         __ATOMIC_RELAXED, __HIP_MEMORY_SCOPE_AGENT);
    }
    // barrier B also restores the hLDS-overwrite safety argument: pollers
    // cannot re-enter the poll (and overwrite hLDS) before every wave's
    // compute-phase hLDS reads are done.
  }
}

// ---------------- states output: hdec * valid ----------------
__global__ __launch_bounds__(256) void states_kernel(
    const float* __restrict__ hdec, const float* __restrict__ valid,
    float* __restrict__ out2)
{
  int i = blockIdx.x * 256 + threadIdx.x;
  out2[i] = hdec[i] * valid[i >> 10];
}

extern "C" void kernel_launch(void* const* d_in, const int* in_sizes, int n_in,
                              void* d_out, int out_size, void* d_ws, size_t ws_size,
                              hipStream_t stream)
{
  const int*   char_seq  = (const int*)  d_in[0];
  const int*   target    = (const int*)  d_in[1];
  const float* enc_state = (const float*)d_in[2];
  const float* emb       = (const float*)d_in[3];
  const float* enc_wih   = (const float*)d_in[4];
  const float* enc_whh   = (const float*)d_in[5];
  const float* enc_bih   = (const float*)d_in[6];
  const float* enc_bhh   = (const float*)d_in[7];
  const float* dec_wih   = (const float*)d_in[8];
  const float* dec_whh   = (const float*)d_in[9];
  const float* dec_bih   = (const float*)d_in[10];
  const float* dec_bhh   = (const float*)d_in[11];
  const float* out_w     = (const float*)d_in[12];
  const float* out_b     = (const float*)d_in[13];
  const int*   sos_p     = (const int*)  d_in[14];
  const int*   eos_p     = (const int*)  d_in[15];

  char* ws = (char*)d_ws;
  float* gi_enc = (float*)ws;  ws += (size_t)SEQ_L * G3 * sizeof(float);
  float* gi_dec = (float*)ws;  ws += (size_t)SEQ_L * G3 * sizeof(float);
  float* hbuf   = (float*)ws;  ws += (size_t)(2 * SEQ_L + 1) * HID * sizeof(float);
  float* valid  = (float*)ws;  ws += SEQ_L * sizeof(float);
  int*   dec_in = (int*)ws;    ws += SEQ_L * sizeof(int);

  // decode step d (1..SEQ_L) writes hbuf row SEQ_L+d  ->  hdec = hbuf[SEQ_L+1]
  float* hdec = hbuf + (size_t)(SEQ_L + 1) * HID;

  float* out_scores = (float*)d_out;
  float* out_states = out_scores + (size_t)SEQ_L * VOCAB;

  prep_kernel<<<1, 1024, 0, stream>>>(target, sos_p, eos_p, dec_in, valid);
  gemm_nt<<<dim3(G3 / 128, SEQ_L / 128), 256, 0, stream>>>(
      emb, char_seq, enc_wih, enc_bih, nullptr, gi_enc, SEQ_L, G3, EMB);
  gemm_nt<<<dim3(G3 / 128, SEQ_L / 128), 256, 0, stream>>>(
      emb, dec_in, dec_wih, dec_bih, nullptr, gi_dec, SEQ_L, G3, EMB);
  recur_kernel<<<NWG, 1024, 0, stream>>>(
      enc_whh, enc_bhh, dec_whh, dec_bhh, enc_state, char_seq,
      gi_enc, gi_dec, hbuf);
  gemm_nt<<<dim3((VOCAB + 127) / 128, SEQ_L / 128), 256, 0, stream>>>(
      hdec, nullptr, out_w, out_b, valid, out_scores, SEQ_L, VOCAB, HID);
  states_kernel<<<(SEQ_L * HID) / 256, 256, 0, stream>>>(hdec, valid, out_states);
}